// Round 5
// baseline (211.041 us; speedup 1.0000x reference)
//
#include <hip/hip_runtime.h>
#include <math.h>

#define NN 8000
#define NE 128000
#define NZ 10
#define KC 128
#define NB8 8
#define HID 64

// ws layout (float offsets)
#define WS_G 0   // 100*64 = 6400 floats (25.6 KB)

// ---- fused prep: blocks 0..99 -> G[pair]; blocks 100..131 -> base + out init
__global__ __launch_bounds__(256)
void k_prep(const float* __restrict__ w_embed, const float* __restrict__ w_up,
            const float* __restrict__ W4, const float* __restrict__ w_lin,
            const float* __restrict__ w_skip, const float* __restrict__ w_sym,
            const float* __restrict__ w_lin2, const float* __restrict__ w_readout,
            const float* __restrict__ ae, const int* __restrict__ species,
            float* __restrict__ ws, float* __restrict__ out)
{
    const int b = blockIdx.x, tid = threadIdx.x;
    if (b < NZ*NZ) {
        // G[zs][zr][c] = (1/16) * sum_kp W4[c,4kp] * hup[zs][kp] * wfin[zr][kp]
        const int zs = b / NZ, zr = b % NZ;
        __shared__ float s_wl[KC];   // wl2r[k] * w_sym[0][zr][k]
        __shared__ float s_hw[KC];   // hup[zs][kp] * wfin[zr][kp]
        if (tid < KC) {
            float acc = 0.f;   // wl2r[tid] = sum_j w_lin2[0][tid][j] * w_readout[j]
            for (int j = 0; j < KC; ++j) acc += w_lin2[tid*KC + j] * w_readout[j];
            s_wl[tid] = acc * w_sym[zr*KC + tid];
        }
        __syncthreads();
        if (tid < KC) {
            float wf = 0.f;    // wfin[zr][tid] = sum_k w_lin[0][tid][k] * s_wl[k]
            for (int k = 0; k < KC; ++k) wf += w_lin[tid*KC + k] * s_wl[k];
            float hu = 0.f;    // hup[zs][tid] = sum_q w_embed[zs][q] * w_up[q][tid]
            for (int q = 0; q < KC; ++q) hu += w_embed[zs*KC + q] * w_up[q*KC + tid];
            s_hw[tid] = hu * wf;
        }
        __syncthreads();
        if (tid < HID) {
            const float* w4row = W4 + tid*(KC*4);   // W4[c][4kp] -> l=0 slice
            float acc = 0.f;
            for (int kp = 0; kp < KC; ++kp) acc += w4row[4*kp] * s_hw[kp];
            ws[WS_G + b*HID + tid] = acc * (1.0f/16.0f);   // fold /AVG_NEIGH
        }
    } else {
        // base[z] computed redundantly per init block, then out[n] = base[species[n]]
        __shared__ float s_base[NZ];
        __shared__ float s_red[KC];
        for (int z = 0; z < NZ; ++z) {
            if (tid < KC) {
                const float* wk = w_skip + (z*KC + tid)*KC;
                float dot = 0.f;
                for (int j = 0; j < KC; ++j) dot += wk[j] * w_readout[j];
                s_red[tid] = w_embed[z*KC + tid] * dot;
            }
            __syncthreads();
            for (int s = 64; s > 0; s >>= 1) {
                if (tid < s) s_red[tid] += s_red[tid + s];
                __syncthreads();
            }
            if (tid == 0) s_base[z] = ae[z] + rsqrtf((float)NZ) * s_red[0];
            __syncthreads();
        }
        const int n = (b - NZ*NZ)*256 + tid;
        if (n < NN) out[n] = s_base[species[n]];
    }
}

// ---- main edge kernel: wave-per-edge, 2 edges/iteration, full-VGPR weights
__global__ __launch_bounds__(256, 2)
void k_edge(const float* __restrict__ pos, const float* __restrict__ shifts,
            const int* __restrict__ eidx, const int* __restrict__ species,
            const float* __restrict__ W1, const float* __restrict__ W2,
            const float* __restrict__ W3, const float* __restrict__ ws,
            float* __restrict__ out)
{
    __shared__ __align__(16) float sT[4][2][HID];   // per-wave, per-edge-slot
    const int tid  = threadIdx.x;
    const int lane = tid & 63;
    const int wid  = tid >> 6;

    float w1r[NB8];
    #pragma unroll
    for (int b = 0; b < NB8; ++b) w1r[b] = W1[b*HID + lane];
    float w2r[HID], w3r[HID];
    #pragma unroll
    for (int c = 0; c < HID; ++c) w2r[c] = W2[c*HID + lane];
    #pragma unroll
    for (int c = 0; c < HID; ++c) w3r[c] = W3[c*HID + lane];

    const float* G = ws + WS_G;
    const int wg   = blockIdx.x * 4 + wid;
    const int wtot = gridDim.x * 4;

    for (int e0 = wg * 2; e0 < NE; e0 += wtot * 2) {
        const int eA = e0, eB = e0 + 1;
        const int sA = eidx[eA], rA = eidx[NE + eA];
        const int sB = eidx[eB], rB = eidx[NE + eB];

        const float dxA = pos[rA*3+0] - pos[sA*3+0] + shifts[eA*3+0];
        const float dyA = pos[rA*3+1] - pos[sA*3+1] + shifts[eA*3+1];
        const float dzA = pos[rA*3+2] - pos[sA*3+2] + shifts[eA*3+2];
        const float dxB = pos[rB*3+0] - pos[sB*3+0] + shifts[eB*3+0];
        const float dyB = pos[rB*3+1] - pos[sB*3+1] + shifts[eB*3+1];
        const float dzB = pos[rB*3+2] - pos[sB*3+2] + shifts[eB*3+2];
        const float r2A = dxA*dxA + dyA*dyA + dzA*dzA + 1e-9f;
        const float r2B = dxB*dxB + dyB*dyB + dzB*dzB + 1e-9f;
        if (r2A >= 25.f && r2B >= 25.f) continue;   // wave-uniform: both dead

        const float rA_ = sqrtf(r2A), rB_ = sqrtf(r2B);
        const float xA = rA_ * 0.2f,  xB = rB_ * 0.2f;

        float envA = 0.f, envB = 0.f;
        {
            const float x2 = xA*xA, x5 = x2*x2*xA;
            if (xA < 1.f) envA = 1.0f + x5*(-21.0f + xA*(35.0f - 15.0f*xA));
        }
        {
            const float x2 = xB*xB, x5 = x2*x2*xB;
            if (xB < 1.f) envB = 1.0f + x5*(-21.0f + xB*(35.0f - 15.0f*xB));
        }
        float s1A, c1A, s1B, c1B;
        __sincosf(3.14159265358979323846f * xA, &s1A, &c1A);
        __sincosf(3.14159265358979323846f * xB, &s1B, &c1B);
        const float tcA = 2.f*c1A, tcB = 2.f*c1B;
        const float prefA = 0.632455532033675866f * envA / rA_;
        const float prefB = 0.632455532033675866f * envB / rB_;

        // layer 1 (8->64), Chebyshev recurrence for sin(n*pi*x)
        float accA = 0.f, accB = 0.f;
        {
            float spA = 0.f, scA = s1A, spB = 0.f, scB = s1B;
            #pragma unroll
            for (int b = 0; b < NB8; ++b) {
                accA += (scA * prefA) * w1r[b];
                accB += (scB * prefB) * w1r[b];
                const float nA = tcA*scA - spA; spA = scA; scA = nA;
                const float nB = tcB*scB - spB; spB = scB; scB = nB;
            }
        }
        const float t1A = accA / (1.0f + __expf(-accA));
        const float t1B = accB / (1.0f + __expf(-accB));

        __builtin_amdgcn_wave_barrier();
        sT[wid][0][lane] = t1A;
        sT[wid][1][lane] = t1B;
        __builtin_amdgcn_wave_barrier();

        // layer 2 (64->64), both edges interleaved
        float a0A=0.f,a1A=0.f,a2A=0.f,a3A=0.f, a0B=0.f,a1B=0.f,a2B=0.f,a3B=0.f;
        #pragma unroll
        for (int q = 0; q < 16; ++q) {
            const float4 tA = *reinterpret_cast<const float4*>(&sT[wid][0][q*4]);
            const float4 tB = *reinterpret_cast<const float4*>(&sT[wid][1][q*4]);
            a0A += tA.x * w2r[4*q+0]; a0B += tB.x * w2r[4*q+0];
            a1A += tA.y * w2r[4*q+1]; a1B += tB.y * w2r[4*q+1];
            a2A += tA.z * w2r[4*q+2]; a2B += tB.z * w2r[4*q+2];
            a3A += tA.w * w2r[4*q+3]; a3B += tB.w * w2r[4*q+3];
        }
        const float z2A = (a0A+a1A)+(a2A+a3A);
        const float z2B = (a0B+a1B)+(a2B+a3B);
        const float t2A = z2A / (1.0f + __expf(-z2A));
        const float t2B = z2B / (1.0f + __expf(-z2B));

        __builtin_amdgcn_wave_barrier();
        sT[wid][0][lane] = t2A;
        sT[wid][1][lane] = t2B;
        __builtin_amdgcn_wave_barrier();

        // layer 3 (64->64)
        a0A=0.f;a1A=0.f;a2A=0.f;a3A=0.f; a0B=0.f;a1B=0.f;a2B=0.f;a3B=0.f;
        #pragma unroll
        for (int q = 0; q < 16; ++q) {
            const float4 tA = *reinterpret_cast<const float4*>(&sT[wid][0][q*4]);
            const float4 tB = *reinterpret_cast<const float4*>(&sT[wid][1][q*4]);
            a0A += tA.x * w3r[4*q+0]; a0B += tB.x * w3r[4*q+0];
            a1A += tA.y * w3r[4*q+1]; a1B += tB.y * w3r[4*q+1];
            a2A += tA.z * w3r[4*q+2]; a2B += tB.z * w3r[4*q+2];
            a3A += tA.w * w3r[4*q+3]; a3B += tB.w * w3r[4*q+3];
        }
        const float z3A = (a0A+a1A)+(a2A+a3A);
        const float z3B = (a0B+a1B)+(a2B+a3B);
        const float t3A = z3A / (1.0f + __expf(-z3A));
        const float t3B = z3B / (1.0f + __expf(-z3B));

        // per-pair G row (L1-resident 25.6 KB table) + wave reduce + atomic
        const int pA = species[sA]*NZ + species[rA];
        const int pB = species[sB]*NZ + species[rB];
        float vA = t3A * G[pA*HID + lane];
        float vB = t3B * G[pB*HID + lane];
        #pragma unroll
        for (int off = 32; off > 0; off >>= 1) {
            vA += __shfl_xor(vA, off);
            vB += __shfl_xor(vB, off);
        }
        if (lane == 0) {
            atomicAdd(&out[rA], vA);
            atomicAdd(&out[rB], vB);
        }
    }
}

extern "C" void kernel_launch(void* const* d_in, const int* in_sizes, int n_in,
                              void* d_out, int out_size, void* d_ws, size_t ws_size,
                              hipStream_t stream)
{
    const float* positions  = (const float*)d_in[0];
    const float* shifts     = (const float*)d_in[1];
    const int*   edge_index = (const int*)  d_in[2];
    const int*   species    = (const int*)  d_in[3];
    const float* ae         = (const float*)d_in[4];
    const float* w_embed    = (const float*)d_in[5];
    const float* w_up       = (const float*)d_in[6];
    const float* W1         = (const float*)d_in[7];
    const float* W2         = (const float*)d_in[8];
    const float* W3         = (const float*)d_in[9];
    const float* W4         = (const float*)d_in[10];
    const float* w_lin      = (const float*)d_in[11];
    const float* w_skip     = (const float*)d_in[12];
    const float* w_sym      = (const float*)d_in[13];
    const float* w_lin2     = (const float*)d_in[14];
    const float* w_readout  = (const float*)d_in[15];
    float* out = (float*)d_out;
    float* ws  = (float*)d_ws;

    // blocks 0..99: G pairs; blocks 100..131: base + out init (8192 >= 8000)
    k_prep<<<NZ*NZ + 32, 256, 0, stream>>>(w_embed, w_up, W4, w_lin, w_skip,
                                           w_sym, w_lin2, w_readout, ae,
                                           species, ws, out);
    k_edge<<<2048, 256, 0, stream>>>(positions, shifts, edge_index, species,
                                     W1, W2, W3, ws, out);
}

// Round 7
// 206.464 us; speedup vs baseline: 1.0222x; 1.0222x over previous
//
#include <hip/hip_runtime.h>
#include <math.h>

#define NN 8000
#define NE 128000
#define NZ 10
#define KC 128
#define HID 64

// ws layout (float offsets)
#define WS_G    0       // 100*64 = 6400
#define WS_BASE 6400    // 10 (+6 pad)
#define WS_HUP  6416    // 10*128 = 1280
#define WS_WL2R 7696    // 128  -> total 7824 floats (31.3 KB)

// ---------- prep 1: blocks 0..9 -> hup[z], base[z]; block 10 -> wl2r ----------
__global__ __launch_bounds__(256)
void kP1(const float* __restrict__ w_embed, const float* __restrict__ w_up,
         const float* __restrict__ w_lin2, const float* __restrict__ w_readout,
         const float* __restrict__ w_skip, const float* __restrict__ ae,
         float* __restrict__ ws)
{
    const int b = blockIdx.x, tid = threadIdx.x;
    if (b < NZ) {
        const int z = b;
        // hup[z][t] = sum_kp w_embed[z][kp] * w_up[kp][t]  (coalesced over t)
        if (tid < KC) {
            float acc = 0.f;
            for (int kp = 0; kp < KC; ++kp)
                acc = fmaf(w_embed[z*KC + kp], w_up[kp*KC + tid], acc);
            ws[WS_HUP + z*KC + tid] = acc;
        }
        // base[z] = ae[z] + (1/sqrt(10)) * sum_{k,j} w_skip[z][k][j]*wr[j]*we[k]
        __shared__ float s_wr[KC], s_we[KC];
        __shared__ float s_red[256];
        if (tid < KC) { s_wr[tid] = w_readout[tid]; s_we[tid] = w_embed[z*KC + tid]; }
        __syncthreads();
        float part = 0.f;
        for (int i = tid; i < KC*KC; i += 256)           // i = k*128 + j, coalesced
            part = fmaf(w_skip[z*KC*KC + i], s_wr[i & 127] * s_we[i >> 7], part);
        s_red[tid] = part; __syncthreads();
        for (int s = 128; s > 0; s >>= 1) {
            if (tid < s) s_red[tid] += s_red[tid + s];
            __syncthreads();
        }
        if (tid == 0) ws[WS_BASE + z] = ae[z] + rsqrtf(10.f) * s_red[0];
    } else {
        // wl2r[r] = dot(w_lin2[0][r][:], w_readout)  — wave-per-row, lane-split
        const int lane = tid & 63, wid = tid >> 6;
        const float2 wr2 = *reinterpret_cast<const float2*>(w_readout + 2*lane);
        for (int i = 0; i < 32; ++i) {
            const int r = wid*32 + i;
            const float2 wl = *reinterpret_cast<const float2*>(w_lin2 + r*KC + 2*lane);
            float p = wl.x*wr2.x + wl.y*wr2.y;
            #pragma unroll
            for (int off = 32; off > 0; off >>= 1) p += __shfl_xor(p, off);
            if (lane == 0) ws[WS_WL2R + r] = p;
        }
    }
}

// ---------- prep 2: blocks 0..99 -> G[pair]; blocks 100..131 -> out init ----------
__global__ __launch_bounds__(256)
void kP2(const float* __restrict__ w_lin, const float* __restrict__ w_sym,
         const float* __restrict__ W4, const int* __restrict__ species,
         float* __restrict__ ws, float* __restrict__ out)
{
    const int b = blockIdx.x, tid = threadIdx.x;
    if (b < NZ*NZ) {
        const int zs = b / NZ, zr = b % NZ;
        __shared__ float s_sw[KC];   // wl2r[k] * w_sym[0][zr][k]
        __shared__ float s_hw[KC];   // hup[zs][t] * wfin[zr][t]
        if (tid < KC) s_sw[tid] = ws[WS_WL2R + tid] * w_sym[zr*KC + tid];
        __syncthreads();
        const int lane = tid & 63, wid = tid >> 6;
        const float swx = s_sw[2*lane], swy = s_sw[2*lane + 1];
        // wfin rows: 4 waves x 32 rows, lane-split coalesced
        for (int i = 0; i < 32; ++i) {
            const int t = wid*32 + i;
            const float2 wl = *reinterpret_cast<const float2*>(w_lin + t*KC + 2*lane);
            float p = wl.x*swx + wl.y*swy;
            #pragma unroll
            for (int off = 32; off > 0; off >>= 1) p += __shfl_xor(p, off);
            if (lane == 0) s_hw[t] = p * ws[WS_HUP + zs*KC + t];
        }
        __syncthreads();
        const float hx = s_hw[lane], hy = s_hw[64 + lane];
        // G rows: 4 waves x 16 rows; W4 l=0 slice is col 4*kp
        for (int i = 0; i < 16; ++i) {
            const int c = wid*16 + i;
            const float a0 = W4[c*(KC*4) + 4*lane];          // kp = lane
            const float a1 = W4[c*(KC*4) + 256 + 4*lane];    // kp = 64+lane
            float p = a0*hx + a1*hy;
            #pragma unroll
            for (int off = 32; off > 0; off >>= 1) p += __shfl_xor(p, off);
            if (lane == 0) ws[WS_G + b*HID + c] = p * (1.0f/16.0f);
        }
    } else {
        const int n = (b - NZ*NZ)*256 + tid;
        if (n < NN) out[n] = ws[WS_BASE + species[n]];
    }
}

// ---------- main: edge-per-lane, weights via lane-uniform (scalar) loads ----------
#define LAYER64(W, IN, OUT)                                             \
    _Pragma("unroll")                                                   \
    for (int c = 0; c < 16; ++c) {                                      \
        const float4 wv = *reinterpret_cast<const float4*>((W) + 4*c);  \
        OUT[4*c+0] = wv.x * IN[0]; OUT[4*c+1] = wv.y * IN[0];           \
        OUT[4*c+2] = wv.z * IN[0]; OUT[4*c+3] = wv.w * IN[0];           \
    }                                                                   \
    _Pragma("unroll")                                                   \
    for (int k = 1; k < 64; ++k) {                                      \
        const float tk = IN[k];                                         \
        _Pragma("unroll")                                               \
        for (int q = 0; q < 16; ++q) {                                  \
            const float4 wv = *reinterpret_cast<const float4*>((W) + k*64 + 4*q); \
            OUT[4*q+0] = fmaf(wv.x, tk, OUT[4*q+0]);                    \
            OUT[4*q+1] = fmaf(wv.y, tk, OUT[4*q+1]);                    \
            OUT[4*q+2] = fmaf(wv.z, tk, OUT[4*q+2]);                    \
            OUT[4*q+3] = fmaf(wv.w, tk, OUT[4*q+3]);                    \
        }                                                               \
    }

__global__ __launch_bounds__(256, 2)
void k_edge(const float* __restrict__ pos, const float* __restrict__ shifts,
            const int* __restrict__ eidx, const int* __restrict__ species,
            const float* __restrict__ W1, const float* __restrict__ W2,
            const float* __restrict__ W3, const float* __restrict__ ws,
            float* __restrict__ out)
{
    __shared__ float sG[NZ*NZ*65];   // stride-65 pad: bank = (p+c)%32
    const int tid = threadIdx.x;
    for (int i = tid; i < NZ*NZ*HID; i += 256)
        sG[(i >> 6)*65 + (i & 63)] = ws[WS_G + i];
    __syncthreads();

    const int lane = tid & 63;
    const int e = (blockIdx.x*4 + (tid >> 6))*64 + lane;   // 500*4*64 = 128000 exactly

    const int sI = eidx[e];
    const int rI = eidx[NE + e];
    const float dx = pos[rI*3+0] - pos[sI*3+0] + shifts[e*3+0];
    const float dy = pos[rI*3+1] - pos[sI*3+1] + shifts[e*3+1];
    const float dz = pos[rI*3+2] - pos[sI*3+2] + shifts[e*3+2];
    const float r2 = dx*dx + dy*dy + dz*dz + 1e-9f;
    const float r  = sqrtf(r2);
    const float x  = r * 0.2f;

    float env = 0.f;
    if (x < 1.f) {
        const float x2 = x*x, x5 = x2*x2*x;
        env = 1.0f + x5*(-21.0f + x*(35.0f - 15.0f*x));
    }
    float s1, c1;
    __sincosf(3.14159265358979323846f * x, &s1, &c1);
    const float tc   = 2.0f*c1;
    const float pref = 0.632455532033675866f * env / r;

    // ef[b] = sin((b+1)*pi*x) * pref  via Chebyshev recurrence (static unroll)
    float ef[8];
    {
        float sp = 0.f, sc = s1;
        #pragma unroll
        for (int b = 0; b < 8; ++b) {
            ef[b] = sc * pref;
            const float nx = tc*sc - sp; sp = sc; sc = nx;
        }
    }

    float t[64], u[64];
    // layer 1: 8 -> 64
    #pragma unroll
    for (int q = 0; q < 16; ++q) {
        const float4 wv = *reinterpret_cast<const float4*>(W1 + 4*q);
        t[4*q+0] = wv.x * ef[0]; t[4*q+1] = wv.y * ef[0];
        t[4*q+2] = wv.z * ef[0]; t[4*q+3] = wv.w * ef[0];
    }
    #pragma unroll
    for (int b = 1; b < 8; ++b) {
        const float tk = ef[b];
        #pragma unroll
        for (int q = 0; q < 16; ++q) {
            const float4 wv = *reinterpret_cast<const float4*>(W1 + b*64 + 4*q);
            t[4*q+0] = fmaf(wv.x, tk, t[4*q+0]);
            t[4*q+1] = fmaf(wv.y, tk, t[4*q+1]);
            t[4*q+2] = fmaf(wv.z, tk, t[4*q+2]);
            t[4*q+3] = fmaf(wv.w, tk, t[4*q+3]);
        }
    }
    #pragma unroll
    for (int c = 0; c < 64; ++c) u[c] = t[c] / (1.f + __expf(-t[c]));

    // layer 2: 64 -> 64 (weights lane-uniform -> scalar loads)
    LAYER64(W2, u, t)
    #pragma unroll
    for (int c = 0; c < 64; ++c) u[c] = t[c] / (1.f + __expf(-t[c]));

    // layer 3: 64 -> 64
    LAYER64(W3, u, t)

    // silu + dot with per-pair G row (LDS, stride-65)
    const int p = species[sI]*NZ + species[rI];
    const int gb = p*65;
    float acc = 0.f;
    #pragma unroll
    for (int c = 0; c < 64; ++c) {
        const float z3 = t[c];
        const float s  = z3 / (1.f + __expf(-z3));
        acc = fmaf(s, sG[gb + c], acc);
    }
    if (x < 1.f) atomicAdd(&out[rI], acc);
}

extern "C" void kernel_launch(void* const* d_in, const int* in_sizes, int n_in,
                              void* d_out, int out_size, void* d_ws, size_t ws_size,
                              hipStream_t stream)
{
    const float* positions  = (const float*)d_in[0];
    const float* shifts     = (const float*)d_in[1];
    const int*   edge_index = (const int*)  d_in[2];
    const int*   species    = (const int*)  d_in[3];
    const float* ae         = (const float*)d_in[4];
    const float* w_embed    = (const float*)d_in[5];
    const float* w_up       = (const float*)d_in[6];
    const float* W1         = (const float*)d_in[7];
    const float* W2         = (const float*)d_in[8];
    const float* W3         = (const float*)d_in[9];
    const float* W4         = (const float*)d_in[10];
    const float* w_lin      = (const float*)d_in[11];
    const float* w_skip     = (const float*)d_in[12];
    const float* w_sym      = (const float*)d_in[13];
    const float* w_lin2     = (const float*)d_in[14];
    const float* w_readout  = (const float*)d_in[15];
    float* out = (float*)d_out;
    float* ws  = (float*)d_ws;

    kP1<<<NZ + 1, 256, 0, stream>>>(w_embed, w_up, w_lin2, w_readout, w_skip, ae, ws);
    kP2<<<NZ*NZ + 32, 256, 0, stream>>>(w_lin, w_sym, W4, species, ws, out);
    k_edge<<<NE/256, 256, 0, stream>>>(positions, shifts, edge_index, species,
                                       W1, W2, W3, ws, out);
}